// Round 11
// baseline (640.360 us; speedup 1.0000x reference)
//
#include <hip/hip_runtime.h>
#include <hip/hip_bf16.h>
#include <float.h>

#define BATCH 8
#define CDIM 64
#define NPTS 4096
#define KNN 20
#define KSEL 32
#define BUFCAP 56
#define BN_EPS 1e-5f
#define NEG_SLOPE 0.2f

typedef __attribute__((ext_vector_type(8))) short short8;
typedef __attribute__((ext_vector_type(4))) float float4v;
typedef unsigned short ushort;
typedef unsigned int uint;
typedef unsigned long long ull;

__device__ __forceinline__ ushort f2bf(float f) {
    uint u = __float_as_uint(f);
    u += 0x7FFF + ((u >> 16) & 1);            // round-to-nearest-even
    return (ushort)(u >> 16);
}
__device__ __forceinline__ float bf2f(ushort h) {
    return __uint_as_float(((uint)h) << 16);
}
__device__ __forceinline__ int mbcnt64(ull m) {
    int c = __builtin_amdgcn_mbcnt_lo((uint)m, 0);
    return __builtin_amdgcn_mbcnt_hi((uint)(m >> 32), c);
}

// Exact 32-smallest of {buf[0..cnt)} U {key[lane]}; compacts to buf front,
// sets cnt (<=32), returns K33 threshold. Requires cnt <= 64 on entry.
__device__ __forceinline__ uint select32_merge(uint* __restrict__ buf,
                                               int& cnt, int lane, uint key) {
    uint e0 = (lane < cnt) ? buf[lane] : 0xFFFFFFFFu;
    uint e1 = key;
    uint p = 0;
    for (int bit = 31; bit >= 0; --bit) {
        uint t = p | (1u << bit);
        int c = __popcll(__ballot(e0 < t)) + __popcll(__ballot(e1 < t));
        if (c < 33) p = t;   // uniform
    }
    ull m0 = __ballot(e0 < p);
    ull m1 = __ballot(e1 < p);
    int c0 = __popcll(m0);
    int r0 = mbcnt64(m0);
    int r1 = c0 + mbcnt64(m1);
    if (e0 < p) buf[r0] = e0;
    if (e1 < p) buf[r1] = e1;
    cnt = c0 + __popcll(m1);
    return p;
}

// ---------------------------------------------------------------------------
// K1: x [B,C,N] -> xt [B,N,64] fp32, xh/xl bf16 hi/lo split, sq[b,n].
// ---------------------------------------------------------------------------
__global__ void k_prep(const float* __restrict__ x,
                       float* __restrict__ xt,
                       ushort* __restrict__ xh,
                       ushort* __restrict__ xl,
                       float* __restrict__ sq) {
    int gid = blockIdx.x * 256 + threadIdx.x;     // [0, B*N)
    int b = gid >> 12;
    int n = gid & (NPTS - 1);
    const float* xb = x + (size_t)b * CDIM * NPTS + n;
    float acc = 0.f;
    float4* xtv = (float4*)(xt + ((size_t)gid << 6));
    uint2* xhp = (uint2*)(xh + ((size_t)gid << 6));
    uint2* xlp = (uint2*)(xl + ((size_t)gid << 6));
    #pragma unroll
    for (int q = 0; q < 16; ++q) {
        float v[4]; ushort h[4], l[4];
        #pragma unroll
        for (int j = 0; j < 4; ++j) {
            float tv = xb[(q * 4 + j) * NPTS];    // coalesced across n
            v[j] = tv;
            acc = fmaf(tv, tv, acc);
            h[j] = f2bf(tv);
            l[j] = f2bf(tv - bf2f(h[j]));
        }
        xtv[q] = make_float4(v[0], v[1], v[2], v[3]);
        uint2 ph, pl;
        ph.x = (uint)h[0] | ((uint)h[1] << 16);
        ph.y = (uint)h[2] | ((uint)h[3] << 16);
        pl.x = (uint)l[0] | ((uint)l[1] << 16);
        pl.y = (uint)l[2] | ((uint)l[3] << 16);
        xhp[q] = ph;
        xlp[q] = pl;
    }
    sq[gid] = acc;
}

// ---------------------------------------------------------------------------
// K2: p = W1 @ x, z = (W2-W1) @ x, stored transposed: pt/zt [B,N,64]
// ---------------------------------------------------------------------------
__global__ void k_pz(const float* __restrict__ xt, const float* __restrict__ W,
                     float* __restrict__ pt, float* __restrict__ zt) {
    int b  = blockIdx.x >> 6;
    int n0 = (blockIdx.x & 63) << 6;
    int lane = threadIdx.x & 63;
    int w = threadIdx.x >> 6;
    int n = n0 + lane;
    size_t rowoff = ((size_t)(b * NPTS + n)) << 6;
    const float4* xrow = (const float4*)(xt + rowoff);
    float acc1[16], acc2[16];
    #pragma unroll
    for (int i = 0; i < 16; ++i) { acc1[i] = 0.f; acc2[i] = 0.f; }
    #pragma unroll
    for (int cg = 0; cg < 4; ++cg) {
        float xv[16];
        #pragma unroll
        for (int q = 0; q < 4; ++q) {
            float4 t = xrow[cg * 4 + q];
            xv[q*4] = t.x; xv[q*4+1] = t.y; xv[q*4+2] = t.z; xv[q*4+3] = t.w;
        }
        #pragma unroll
        for (int oi = 0; oi < 16; ++oi) {
            int o = (w << 4) + oi;
            const float* wr = W + o * 128 + cg * 16;
            float a1 = acc1[oi], a2 = acc2[oi];
            #pragma unroll
            for (int j = 0; j < 16; ++j) {
                a1 = fmaf(wr[j],      xv[j], a1);
                a2 = fmaf(wr[64 + j], xv[j], a2);
            }
            acc1[oi] = a1; acc2[oi] = a2;
        }
    }
    float4* pv = (float4*)(pt + rowoff + (w << 4));
    float4* zv = (float4*)(zt + rowoff + (w << 4));
    #pragma unroll
    for (int q = 0; q < 4; ++q) {
        pv[q] = make_float4(acc1[q*4], acc1[q*4+1], acc1[q*4+2], acc1[q*4+3]);
        zv[q] = make_float4(acc2[q*4]   - acc1[q*4],
                            acc2[q*4+1] - acc1[q*4+1],
                            acc2[q*4+2] - acc1[q*4+2],
                            acc2[q*4+3] - acc1[q*4+3]);
    }
}

// ---------------------------------------------------------------------------
// K3: zero-barrier split-bf16 MFMA kNN. One wave per block; wave owns 16
// rows and scans all 4096 candidates in 64-cand chunks. B-fragments read
// directly from global (L2-resident); C->scan transpose via wave-private
// LDS (lgkmcnt ordering only — NO __syncthreads anywhere). Selection =
// packed-key (20-bit dist | 12-bit idx) mbcnt-append into 56-entry LDS
// buffer per row; capacity-safe 2-source merge-select on overflow.
// ---------------------------------------------------------------------------
__global__ void __launch_bounds__(64) k_knn(
        const ushort* __restrict__ xh, const ushort* __restrict__ xl,
        const float* __restrict__ sq, ushort* __restrict__ knn32) {
    __shared__ float dw[16][66];          // 4.2 KB, conflict-free strides
    __shared__ uint rowbuf[16 * BUFCAP];  // 3.6 KB

    int lane = threadIdx.x;               // single wave
    int b  = blockIdx.x >> 8;             // 256 blocks per batch
    int r0 = (blockIdx.x & 255) << 4;     // this wave's 16 rows
    int col = lane & 15;
    int quad = lane >> 4;

    // A fragments (chunk-invariant): row = r0 + col, k = quad*8 + j
    size_t arow = ((size_t)(b * NPTS + r0 + col)) << 6;
    short8 ah0 = *(const short8*)(xh + arow + quad * 8);
    short8 ah1 = *(const short8*)(xh + arow + 32 + quad * 8);
    short8 al0 = *(const short8*)(xl + arow + quad * 8);
    short8 al1 = *(const short8*)(xl + arow + 32 + quad * 8);

    const ushort* xhb = xh + (((size_t)b * NPTS) << 6);
    const ushort* xlb = xl + (((size_t)b * NPTS) << 6);
    const float* sqb = sq + b * NPTS;

    uint tau[16]; int cnt[16]; float sqr[16];
    #pragma unroll
    for (int r = 0; r < 16; ++r) {
        tau[r] = 0xFFFFFFFFu; cnt[r] = 0;
        sqr[r] = sqb[r0 + r];             // wave-uniform -> scalar loads
    }

    for (int chunk = 0; chunk < 64; ++chunk) {
        int m0 = chunk << 6;
        float sv = sqb[m0 + lane];        // candidate sq (issued early)

        // 4 tiles of 16 candidates: direct-from-global B-frags + 6 MFMAs
        #pragma unroll
        for (int u = 0; u < 4; ++u) {
            const ushort* ph = xhb + (size_t)(m0 + (u << 4) + col) * 64 + quad * 8;
            const ushort* pl = xlb + (size_t)(m0 + (u << 4) + col) * 64 + quad * 8;
            short8 bh0 = *(const short8*)ph;
            short8 bh1 = *(const short8*)(ph + 32);
            short8 bl0 = *(const short8*)pl;
            short8 bl1 = *(const short8*)(pl + 32);
            float4v acc = {0.f, 0.f, 0.f, 0.f};
            acc = __builtin_amdgcn_mfma_f32_16x16x32_bf16(ah0, bh0, acc, 0, 0, 0);
            acc = __builtin_amdgcn_mfma_f32_16x16x32_bf16(ah1, bh1, acc, 0, 0, 0);
            acc = __builtin_amdgcn_mfma_f32_16x16x32_bf16(ah0, bl0, acc, 0, 0, 0);
            acc = __builtin_amdgcn_mfma_f32_16x16x32_bf16(ah1, bl1, acc, 0, 0, 0);
            acc = __builtin_amdgcn_mfma_f32_16x16x32_bf16(al0, bh0, acc, 0, 0, 0);
            acc = __builtin_amdgcn_mfma_f32_16x16x32_bf16(al1, bh1, acc, 0, 0, 0);
            // C/D: row = quad*4 + r, cand = u*16 + col; conflict-free stride 66
            #pragma unroll
            for (int r = 0; r < 4; ++r)
                dw[(quad << 2) + r][(u << 4) + col] = acc[r];
        }
        // wave-private LDS: same-wave lgkmcnt ordering suffices (no barrier)

        // scan all 16 rows; lane = candidate
        #pragma unroll
        for (int r = 0; r < 16; ++r) {
            float dval = fmaf(-2.f, dw[r][lane], sv + sqr[r]);
            dval = fmaxf(dval, 0.f);
            uint key = (__float_as_uint(dval) & 0xFFFFF000u) | (uint)(m0 + lane);
            uint* bufr = rowbuf + r * BUFCAP;
            ull mask = __ballot(key < tau[r]);
            if (mask) {
                int c = __popcll(mask);
                if (cnt[r] + c > BUFCAP) {
                    tau[r] = select32_merge(bufr, cnt[r], lane, key);
                } else {
                    if (key < tau[r]) bufr[cnt[r] + mbcnt64(mask)] = key;
                    cnt[r] += c;
                }
            }
        }
    }

    // tail: exact top-32 per row -> knn32 indices
    #pragma unroll
    for (int r = 0; r < 16; ++r) {
        uint* bufr = rowbuf + r * BUFCAP;
        select32_merge(bufr, cnt[r], lane, 0xFFFFFFFFu);
        if (lane < KSEL)
            knn32[(size_t)(b * NPTS + r0 + r) * KSEL + lane] =
                (ushort)(bufr[lane] & 0xFFFu);
    }
}

// ---------------------------------------------------------------------------
// K3b: exact fp32 refinement — one wave per row; lanes (mod 32) hold the 32
// candidates, recompute exact fp32 distances, rank lexicographically
// (dist, idx) to match np's lower-index-first tie rule, emit top-20 set.
// ---------------------------------------------------------------------------
__global__ void __launch_bounds__(256) k_refine(
        const float* __restrict__ xt, const float* __restrict__ sq,
        const ushort* __restrict__ knn32, int* __restrict__ idx20) {
    int wid = (blockIdx.x << 2) + (threadIdx.x >> 6);  // row id [0, B*N)
    int lane = threadIdx.x & 63;
    int b = wid >> 12;
    int cand = knn32[(size_t)wid * KSEL + (lane & (KSEL - 1))];
    const float4* xc = (const float4*)(xt + ((size_t)(b * NPTS + cand) << 6));
    const float4* xr = (const float4*)(xt + ((size_t)wid << 6));
    float acc = 0.f;
    #pragma unroll
    for (int q = 0; q < 16; ++q) {
        float4 a = xr[q], c = xc[q];
        acc = fmaf(a.x, c.x, acc); acc = fmaf(a.y, c.y, acc);
        acc = fmaf(a.z, c.z, acc); acc = fmaf(a.w, c.w, acc);
    }
    float d = fmaf(-2.f, acc, sq[b * NPTS + cand]);
    int rank = 0;
    #pragma unroll
    for (int j = 0; j < KSEL; ++j) {
        float dj = __shfl(d, j);
        int   cj = __shfl(cand, j);
        rank += ((dj < d) || (dj == d && cj < cand)) ? 1 : 0;
    }
    if (lane < KSEL && rank < KNN)
        idx20[(size_t)wid * KNN + rank] = cand;
}

// ---------------------------------------------------------------------------
// K4: gather p columns per neighbor; per-(b,n) max/min/sum/sumsq over k;
// write tmax/tmin = (max/min_k p[idx]) + z; accumulate channel sums.
// ---------------------------------------------------------------------------
__global__ void k_gather(const float* __restrict__ pt, const float* __restrict__ zt,
                         const int* __restrict__ idxin,
                         float* __restrict__ tmax, float* __restrict__ tmin,
                         float* __restrict__ S1, float* __restrict__ S2) {
    __shared__ float red1[4][64];
    __shared__ float red2[4][64];
    int b  = blockIdx.x >> 6;
    int n0 = (blockIdx.x & 63) << 6;
    int lane = threadIdx.x & 63;
    int w = threadIdx.x >> 6;
    float cs1 = 0.f, cs2 = 0.f;
    for (int i = 0; i < 16; ++i) {
        int n = n0 + (w << 4) + i;
        int base = b * NPTS + n;
        int ibase = __builtin_amdgcn_readfirstlane(base * KNN);
        const int* ip = idxin + ibase;
        float mx = -FLT_MAX, mn = FLT_MAX, s1 = 0.f, s2 = 0.f;
        #pragma unroll
        for (int k = 0; k < KNN; ++k) {
            int colp = ip[k];                              // SGPR
            float v = pt[(((size_t)(b * NPTS + colp)) << 6) + lane]; // coalesced
            mx = fmaxf(mx, v); mn = fminf(mn, v);
            s1 += v; s2 = fmaf(v, v, s2);
        }
        float z = zt[(((size_t)base) << 6) + lane];
        tmax[(((size_t)base) << 6) + lane] = mx + z;
        tmin[(((size_t)base) << 6) + lane] = mn + z;
        cs1 += s1 + (float)KNN * z;
        cs2 += s2 + 2.f * z * s1 + (float)KNN * z * z;
    }
    red1[w][lane] = cs1;
    red2[w][lane] = cs2;
    __syncthreads();
    if (threadIdx.x < 64) {
        float t1 = red1[0][lane] + red1[1][lane] + red1[2][lane] + red1[3][lane];
        float t2 = red2[0][lane] + red2[1][lane] + red2[2][lane] + red2[3][lane];
        atomicAdd(&S1[lane], t1);
        atomicAdd(&S2[lane], t2);
    }
}

// ---------------------------------------------------------------------------
// K5: finalize BN stats, affine + LeakyReLU, transpose to out [B,64,N].
// ---------------------------------------------------------------------------
__global__ void k_final(const float* __restrict__ tmax, const float* __restrict__ tmin,
                        const float* __restrict__ S1, const float* __restrict__ S2,
                        const float* __restrict__ gamma, const float* __restrict__ beta,
                        float* __restrict__ out) {
    __shared__ float smx[64][65];
    __shared__ float smn[64][65];
    int b  = blockIdx.x >> 6;
    int n0 = (blockIdx.x & 63) << 6;
    int lane = threadIdx.x & 63;
    int w = threadIdx.x >> 6;
    #pragma unroll
    for (int i = 0; i < 16; ++i) {
        int nl = (i << 2) + w;
        size_t off = (((size_t)(b * NPTS + n0 + nl)) << 6) + lane;
        smx[nl][lane] = tmax[off];
        smn[nl][lane] = tmin[off];
    }
    __syncthreads();
    const float inv_cnt = 1.0f / ((float)BATCH * NPTS * KNN);
    #pragma unroll
    for (int i = 0; i < 16; ++i) {
        int o = (i << 2) + w;
        float s1 = S1[o], s2 = S2[o];
        float mean = s1 * inv_cnt;
        float var = fmaf(-mean, mean, s2 * inv_cnt);
        float rs = rsqrtf(var + BN_EPS);
        float sc = gamma[o] * rs;
        float sh = beta[o] - mean * sc;
        float tv = (sc >= 0.f) ? smx[lane][o] : smn[lane][o];
        float y = fmaf(tv, sc, sh);
        y = (y >= 0.f) ? y : NEG_SLOPE * y;
        out[((size_t)(b * 64 + o)) * NPTS + n0 + lane] = y;
    }
}

// ---------------------------------------------------------------------------
extern "C" void kernel_launch(void* const* d_in, const int* in_sizes, int n_in,
                              void* d_out, int out_size, void* d_ws, size_t ws_size,
                              hipStream_t stream) {
    const float* x     = (const float*)d_in[0];   // [8,64,4096]
    const float* W     = (const float*)d_in[1];   // [64,128]
    const float* gamma = (const float*)d_in[2];   // [64]
    const float* beta  = (const float*)d_in[3];   // [64]
    float* out = (float*)d_out;                   // [8,64,4096]

    float* ws = (float*)d_ws;
    const size_t SECT = (size_t)BATCH * NPTS * 64;      // 2,097,152
    float*  xt    = ws;
    float*  pt    = ws + SECT;
    float*  zt    = ws + 2 * SECT;
    float*  sq    = ws + 3 * SECT;                       // 32768
    float*  S1    = ws + 3 * SECT + 32768;               // 64
    float*  S2    = S1 + 64;
    int*    idx20 = (int*)(ws + 3 * SECT + 32768 + 128); // 655,360 ints
    float*  uA    = ws + 3 * SECT + 32768 + 128 + 655360;
    // union A:
    //   phase 1 (prep..refine): xh | xl | knn32(ushort, B*N*32)
    //   phase 2 (gather..final): tmx | tmn
    ushort* xh    = (ushort*)uA;                         // SECT ushorts
    ushort* xl    = (ushort*)(uA + SECT / 2);            // SECT ushorts
    ushort* knn32 = (ushort*)(uA + SECT);                // B*N*32 ushorts
    float*  tmx   = uA;                                  // SECT floats
    float*  tmn   = uA + SECT;                           // SECT floats
    // total ws use: ~44.7 MB

    hipMemsetAsync(S1, 0, 2 * 64 * sizeof(float), stream);
    k_prep  <<<dim3((BATCH * NPTS) / 256), dim3(256), 0, stream>>>(x, xt, xh, xl, sq);
    k_pz    <<<dim3(BATCH * (NPTS / 64)), dim3(256), 0, stream>>>(xt, W, pt, zt);
    k_knn   <<<dim3(BATCH * 256), dim3(64), 0, stream>>>(xh, xl, sq, knn32);
    k_refine<<<dim3((BATCH * NPTS) / 4), dim3(256), 0, stream>>>(xt, sq, knn32, idx20);
    k_gather<<<dim3(BATCH * (NPTS / 64)), dim3(256), 0, stream>>>(pt, zt, idx20, tmx, tmn, S1, S2);
    k_final <<<dim3(BATCH * (NPTS / 64)), dim3(256), 0, stream>>>(tmx, tmn, S1, S2, gamma, beta, out);
}

// Round 12
// 450.755 us; speedup vs baseline: 1.4206x; 1.4206x over previous
//
#include <hip/hip_runtime.h>
#include <hip/hip_bf16.h>
#include <float.h>

#define BATCH 8
#define CDIM 64
#define NPTS 4096
#define KNN 20
#define KSEL 32
#define BUFCAP 96
#define BN_EPS 1e-5f
#define NEG_SLOPE 0.2f

typedef __attribute__((ext_vector_type(8))) short short8;
typedef __attribute__((ext_vector_type(4))) float float4v;
typedef unsigned short ushort;
typedef unsigned int uint;
typedef unsigned long long ull;

__device__ __forceinline__ ushort f2bf(float f) {
    uint u = __float_as_uint(f);
    u += 0x7FFF + ((u >> 16) & 1);            // round-to-nearest-even
    return (ushort)(u >> 16);
}
__device__ __forceinline__ float bf2f(ushort h) {
    return __uint_as_float(((uint)h) << 16);
}
__device__ __forceinline__ int mbcnt64(ull m) {
    int c = __builtin_amdgcn_mbcnt_lo((uint)m, 0);
    return __builtin_amdgcn_mbcnt_hi((uint)(m >> 32), c);
}

// Find 33rd-smallest key in buf[0..cnt), compact keys < K33 to front,
// set cnt to kept count (==32 when cnt>=33). Returns K33 (new tau).
// Safe with BUFCAP=96: a post-truncate append adds <=64 to cnt=32.
__device__ __forceinline__ uint select33_truncate(uint* __restrict__ buf,
                                                  int& cnt, int lane) {
    uint e0 = 0xFFFFFFFFu, e1 = 0xFFFFFFFFu;
    if (lane < cnt) e0 = buf[lane];
    if (64 + lane < cnt) e1 = buf[64 + lane];
    uint p = 0;
    for (int bit = 31; bit >= 0; --bit) {
        uint t = p | (1u << bit);
        ull mA = __ballot(e0 < t);
        ull mB = __ballot(e1 < t);
        if (__popcll(mA) + __popcll(mB) < 33) p = t;   // uniform
    }
    ull mA = __ballot(e0 < p);
    ull mB = __ballot(e1 < p);
    int pA = __popcll(mA);
    int r0 = mbcnt64(mA);
    int r1 = pA + mbcnt64(mB);
    if (e0 < p) buf[r0] = e0;
    if (e1 < p) buf[r1] = e1;
    cnt = pA + __popcll(mB);
    return p;
}

// ---------------------------------------------------------------------------
// K1: x [B,C,N] -> xt [B,N,64] fp32, xh/xl bf16 hi/lo split, sq[b,n].
// ---------------------------------------------------------------------------
__global__ void k_prep(const float* __restrict__ x,
                       float* __restrict__ xt,
                       ushort* __restrict__ xh,
                       ushort* __restrict__ xl,
                       float* __restrict__ sq) {
    int gid = blockIdx.x * 256 + threadIdx.x;     // [0, B*N)
    int b = gid >> 12;
    int n = gid & (NPTS - 1);
    const float* xb = x + (size_t)b * CDIM * NPTS + n;
    float acc = 0.f;
    float4* xtv = (float4*)(xt + ((size_t)gid << 6));
    uint2* xhp = (uint2*)(xh + ((size_t)gid << 6));
    uint2* xlp = (uint2*)(xl + ((size_t)gid << 6));
    #pragma unroll
    for (int q = 0; q < 16; ++q) {
        float v[4]; ushort h[4], l[4];
        #pragma unroll
        for (int j = 0; j < 4; ++j) {
            float tv = xb[(q * 4 + j) * NPTS];    // coalesced across n
            v[j] = tv;
            acc = fmaf(tv, tv, acc);
            h[j] = f2bf(tv);
            l[j] = f2bf(tv - bf2f(h[j]));
        }
        xtv[q] = make_float4(v[0], v[1], v[2], v[3]);
        uint2 ph, pl;
        ph.x = (uint)h[0] | ((uint)h[1] << 16);
        ph.y = (uint)h[2] | ((uint)h[3] << 16);
        pl.x = (uint)l[0] | ((uint)l[1] << 16);
        pl.y = (uint)l[2] | ((uint)l[3] << 16);
        xhp[q] = ph;
        xlp[q] = pl;
    }
    sq[gid] = acc;
}

// ---------------------------------------------------------------------------
// K2: p = W1 @ x, z = (W2-W1) @ x, stored transposed: pt/zt [B,N,64]
// ---------------------------------------------------------------------------
__global__ void k_pz(const float* __restrict__ xt, const float* __restrict__ W,
                     float* __restrict__ pt, float* __restrict__ zt) {
    int b  = blockIdx.x >> 6;
    int n0 = (blockIdx.x & 63) << 6;
    int lane = threadIdx.x & 63;
    int w = threadIdx.x >> 6;
    int n = n0 + lane;
    size_t rowoff = ((size_t)(b * NPTS + n)) << 6;
    const float4* xrow = (const float4*)(xt + rowoff);
    float acc1[16], acc2[16];
    #pragma unroll
    for (int i = 0; i < 16; ++i) { acc1[i] = 0.f; acc2[i] = 0.f; }
    #pragma unroll
    for (int cg = 0; cg < 4; ++cg) {
        float xv[16];
        #pragma unroll
        for (int q = 0; q < 4; ++q) {
            float4 t = xrow[cg * 4 + q];
            xv[q*4] = t.x; xv[q*4+1] = t.y; xv[q*4+2] = t.z; xv[q*4+3] = t.w;
        }
        #pragma unroll
        for (int oi = 0; oi < 16; ++oi) {
            int o = (w << 4) + oi;
            const float* wr = W + o * 128 + cg * 16;
            float a1 = acc1[oi], a2 = acc2[oi];
            #pragma unroll
            for (int j = 0; j < 16; ++j) {
                a1 = fmaf(wr[j],      xv[j], a1);
                a2 = fmaf(wr[64 + j], xv[j], a2);
            }
            acc1[oi] = a1; acc2[oi] = a2;
        }
    }
    float4* pv = (float4*)(pt + rowoff + (w << 4));
    float4* zv = (float4*)(zt + rowoff + (w << 4));
    #pragma unroll
    for (int q = 0; q < 4; ++q) {
        pv[q] = make_float4(acc1[q*4], acc1[q*4+1], acc1[q*4+2], acc1[q*4+3]);
        zv[q] = make_float4(acc2[q*4]   - acc1[q*4],
                            acc2[q*4+1] - acc1[q*4+1],
                            acc2[q*4+2] - acc1[q*4+2],
                            acc2[q*4+3] - acc1[q*4+3]);
    }
}

// ---------------------------------------------------------------------------
// K3: split-bf16 MFMA kNN (R8-proven structure). 64-candidate chunks, block
// = 8 waves over 2 row-groups of 16 rows; wave t computes ONE 16x16 tile
// into the group dw, then scans rows [4t,4t+4) via packed-key (20-bit dist |
// 12-bit idx) mbcnt-append into a 96-entry LDS buffer/row; ballot-bisection
// select-33 on overflow tightens tau and truncates to 32.
// ---------------------------------------------------------------------------
__global__ void __launch_bounds__(512) k_knn(
        const ushort* __restrict__ xh, const ushort* __restrict__ xl,
        const float* __restrict__ sq, ushort* __restrict__ knn32) {
    __shared__ ushort Bh[64][72];     // +8 pad
    __shared__ ushort Bl[64][72];
    __shared__ float dsq[64];
    __shared__ float dw[2][16][68];   // per-group dist tile, padded
    __shared__ uint rowbuf[32 * BUFCAP];   // 8 waves x 4 rows x 96

    int tid  = threadIdx.x;
    int wv   = tid >> 6;              // wave 0..7
    int lane = tid & 63;
    int g    = wv >> 2;               // row-group 0..1
    int t    = wv & 3;                // wave-in-group
    int b    = blockIdx.x >> 7;       // 128 blocks per batch
    int r0   = ((blockIdx.x & 127) << 5) + (g << 4);   // group base row
    int col  = lane & 15;
    int quad = lane >> 4;

    // A fragments (chunk-invariant): row = r0 + col, k = quad*8 + j
    size_t arow = ((size_t)(b * NPTS + r0 + col)) << 6;
    short8 ah0 = *(const short8*)(xh + arow + quad * 8);
    short8 ah1 = *(const short8*)(xh + arow + 32 + quad * 8);
    short8 al0 = *(const short8*)(xl + arow + quad * 8);
    short8 al1 = *(const short8*)(xl + arow + 32 + quad * 8);

    const ushort* xhb = xh + (((size_t)b * NPTS) << 6);
    const ushort* xlb = xl + (((size_t)b * NPTS) << 6);
    const float* sqb = sq + b * NPTS;
    int spt = tid >> 3, seg = tid & 7;    // 64 pts x 8 segs of 8 ushorts

    uint tau[4];
    int cnt[4];
    float sqr[4];
    uint* buf[4];
    #pragma unroll
    for (int r = 0; r < 4; ++r) {
        tau[r] = 0xFFFFFFFFu; cnt[r] = 0;
        sqr[r] = sqb[r0 + (t << 2) + r];
        buf[r] = rowbuf + ((wv << 2) + r) * BUFCAP;
    }

    // prefetch chunk 0
    uint4 vh, vl; float sqpre = 0.f;
    {
        const uint4* gh = (const uint4*)(xhb + ((size_t)spt << 6));
        const uint4* gl = (const uint4*)(xlb + ((size_t)spt << 6));
        vh = gh[seg]; vl = gl[seg];
        if (wv == 0) sqpre = sqb[lane];
    }

    for (int chunk = 0; chunk < 64; ++chunk) {
        int m0 = chunk << 6;
        __syncthreads();   // prior-iter dw reads + B-frag reads done
        *(uint4*)&Bh[spt][seg * 8] = vh;
        *(uint4*)&Bl[spt][seg * 8] = vl;
        if (wv == 0) dsq[lane] = sqpre;
        __syncthreads();   // B staged

        if (chunk < 63) {
            int m1 = m0 + 64;
            const uint4* gh = (const uint4*)(xhb + ((size_t)(m1 + spt) << 6));
            const uint4* gl = (const uint4*)(xlb + ((size_t)(m1 + spt) << 6));
            vh = gh[seg]; vl = gl[seg];
            if (wv == 0) sqpre = sqb[m1 + lane];
        }

        // this wave's single tile: cands [16t, 16t+16), all 16 rows
        {
            int bp = (t << 4) + col;
            short8 bh0 = *(const short8*)&Bh[bp][quad * 8];
            short8 bh1 = *(const short8*)&Bh[bp][32 + quad * 8];
            short8 bl0 = *(const short8*)&Bl[bp][quad * 8];
            short8 bl1 = *(const short8*)&Bl[bp][32 + quad * 8];
            float4v acc = {0.f, 0.f, 0.f, 0.f};
            acc = __builtin_amdgcn_mfma_f32_16x16x32_bf16(ah0, bh0, acc, 0, 0, 0);
            acc = __builtin_amdgcn_mfma_f32_16x16x32_bf16(ah1, bh1, acc, 0, 0, 0);
            acc = __builtin_amdgcn_mfma_f32_16x16x32_bf16(ah0, bl0, acc, 0, 0, 0);
            acc = __builtin_amdgcn_mfma_f32_16x16x32_bf16(ah1, bl1, acc, 0, 0, 0);
            acc = __builtin_amdgcn_mfma_f32_16x16x32_bf16(al0, bh0, acc, 0, 0, 0);
            acc = __builtin_amdgcn_mfma_f32_16x16x32_bf16(al1, bh1, acc, 0, 0, 0);
            #pragma unroll
            for (int r = 0; r < 4; ++r)
                dw[g][(quad << 2) + r][(t << 4) + col] = acc[r];
        }
        __syncthreads();   // dw complete

        // scan rows [4t, 4t+4); lane = candidate
        float sv = dsq[lane];
        #pragma unroll
        for (int r = 0; r < 4; ++r) {
            float dval = fmaf(-2.f, dw[g][(t << 2) + r][lane], sv + sqr[r]);
            dval = fmaxf(dval, 0.f);
            uint key = (__float_as_uint(dval) & 0xFFFFF000u) | (uint)(m0 + lane);
            ull mask = __ballot(key < tau[r]);
            if (mask) {
                int c = __popcll(mask);
                if (cnt[r] + c > BUFCAP) {
                    tau[r] = select33_truncate(buf[r], cnt[r], lane);
                    mask = __ballot(key < tau[r]);
                    c = __popcll(mask);
                }
                if (c) {
                    int rank = mbcnt64(mask);
                    if (key < tau[r]) buf[r][cnt[r] + rank] = key;
                    cnt[r] += c;
                }
            }
        }
    }

    // final extraction: exact key-top-32 per row
    #pragma unroll
    for (int r = 0; r < 4; ++r) {
        select33_truncate(buf[r], cnt[r], lane);
        if (lane < KSEL) {
            uint e = buf[r][lane];
            knn32[(size_t)(b * NPTS + r0 + (t << 2) + r) * KSEL + lane] =
                (ushort)(e & 0xFFFu);
        }
    }
}

// ---------------------------------------------------------------------------
// K3b: exact fp32 refinement — TWO rows per wave (half-wave per row, no idle
// lanes): 32 candidates in each half's lanes, exact fp32 distances, rank
// lexicographically (dist, idx) per np tie rule, emit top-20 set.
// ---------------------------------------------------------------------------
__global__ void __launch_bounds__(256) k_refine(
        const float* __restrict__ xt, const float* __restrict__ sq,
        const ushort* __restrict__ knn32, int* __restrict__ idx20) {
    int wvid = (blockIdx.x << 2) + (threadIdx.x >> 6);  // wave id [0, B*N/2)
    int lane = threadIdx.x & 63;
    int half = lane >> 5;
    int sl   = lane & 31;
    int row  = (wvid << 1) + half;                      // row id [0, B*N)
    int b = row >> 12;
    int cand = knn32[(size_t)row * KSEL + sl];
    const float4* xc = (const float4*)(xt + ((size_t)(b * NPTS + cand) << 6));
    const float4* xr = (const float4*)(xt + ((size_t)row << 6));
    float acc = 0.f;
    #pragma unroll
    for (int q = 0; q < 16; ++q) {
        float4 a = xr[q], c = xc[q];
        acc = fmaf(a.x, c.x, acc); acc = fmaf(a.y, c.y, acc);
        acc = fmaf(a.z, c.z, acc); acc = fmaf(a.w, c.w, acc);
    }
    float d = fmaf(-2.f, acc, sq[b * NPTS + cand]);
    int rank = 0;
    int base = half << 5;
    #pragma unroll
    for (int j = 0; j < KSEL; ++j) {
        float dj = __shfl(d, base + j);
        int   cj = __shfl(cand, base + j);
        rank += ((dj < d) || (dj == d && cj < cand)) ? 1 : 0;
    }
    if (rank < KNN)
        idx20[(size_t)row * KNN + rank] = cand;
}

// ---------------------------------------------------------------------------
// K4: gather p columns per neighbor; per-(b,n) max/min/sum/sumsq over k;
// write tmax/tmin = (max/min_k p[idx]) + z; accumulate channel sums.
// ---------------------------------------------------------------------------
__global__ void k_gather(const float* __restrict__ pt, const float* __restrict__ zt,
                         const int* __restrict__ idxin,
                         float* __restrict__ tmax, float* __restrict__ tmin,
                         float* __restrict__ S1, float* __restrict__ S2) {
    __shared__ float red1[4][64];
    __shared__ float red2[4][64];
    int b  = blockIdx.x >> 6;
    int n0 = (blockIdx.x & 63) << 6;
    int lane = threadIdx.x & 63;
    int w = threadIdx.x >> 6;
    float cs1 = 0.f, cs2 = 0.f;
    for (int i = 0; i < 16; ++i) {
        int n = n0 + (w << 4) + i;
        int base = b * NPTS + n;
        int ibase = __builtin_amdgcn_readfirstlane(base * KNN);
        const int* ip = idxin + ibase;
        float mx = -FLT_MAX, mn = FLT_MAX, s1 = 0.f, s2 = 0.f;
        #pragma unroll
        for (int k = 0; k < KNN; ++k) {
            int colp = ip[k];                              // SGPR
            float v = pt[(((size_t)(b * NPTS + colp)) << 6) + lane]; // coalesced
            mx = fmaxf(mx, v); mn = fminf(mn, v);
            s1 += v; s2 = fmaf(v, v, s2);
        }
        float z = zt[(((size_t)base) << 6) + lane];
        tmax[(((size_t)base) << 6) + lane] = mx + z;
        tmin[(((size_t)base) << 6) + lane] = mn + z;
        cs1 += s1 + (float)KNN * z;
        cs2 += s2 + 2.f * z * s1 + (float)KNN * z * z;
    }
    red1[w][lane] = cs1;
    red2[w][lane] = cs2;
    __syncthreads();
    if (threadIdx.x < 64) {
        float t1 = red1[0][lane] + red1[1][lane] + red1[2][lane] + red1[3][lane];
        float t2 = red2[0][lane] + red2[1][lane] + red2[2][lane] + red2[3][lane];
        atomicAdd(&S1[lane], t1);
        atomicAdd(&S2[lane], t2);
    }
}

// ---------------------------------------------------------------------------
// K5: finalize BN stats, affine + LeakyReLU, transpose to out [B,64,N].
// ---------------------------------------------------------------------------
__global__ void k_final(const float* __restrict__ tmax, const float* __restrict__ tmin,
                        const float* __restrict__ S1, const float* __restrict__ S2,
                        const float* __restrict__ gamma, const float* __restrict__ beta,
                        float* __restrict__ out) {
    __shared__ float smx[64][65];
    __shared__ float smn[64][65];
    int b  = blockIdx.x >> 6;
    int n0 = (blockIdx.x & 63) << 6;
    int lane = threadIdx.x & 63;
    int w = threadIdx.x >> 6;
    #pragma unroll
    for (int i = 0; i < 16; ++i) {
        int nl = (i << 2) + w;
        size_t off = (((size_t)(b * NPTS + n0 + nl)) << 6) + lane;
        smx[nl][lane] = tmax[off];
        smn[nl][lane] = tmin[off];
    }
    __syncthreads();
    const float inv_cnt = 1.0f / ((float)BATCH * NPTS * KNN);
    #pragma unroll
    for (int i = 0; i < 16; ++i) {
        int o = (i << 2) + w;
        float s1 = S1[o], s2 = S2[o];
        float mean = s1 * inv_cnt;
        float var = fmaf(-mean, mean, s2 * inv_cnt);
        float rs = rsqrtf(var + BN_EPS);
        float sc = gamma[o] * rs;
        float sh = beta[o] - mean * sc;
        float tv = (sc >= 0.f) ? smx[lane][o] : smn[lane][o];
        float y = fmaf(tv, sc, sh);
        y = (y >= 0.f) ? y : NEG_SLOPE * y;
        out[((size_t)(b * 64 + o)) * NPTS + n0 + lane] = y;
    }
}

// ---------------------------------------------------------------------------
extern "C" void kernel_launch(void* const* d_in, const int* in_sizes, int n_in,
                              void* d_out, int out_size, void* d_ws, size_t ws_size,
                              hipStream_t stream) {
    const float* x     = (const float*)d_in[0];   // [8,64,4096]
    const float* W     = (const float*)d_in[1];   // [64,128]
    const float* gamma = (const float*)d_in[2];   // [64]
    const float* beta  = (const float*)d_in[3];   // [64]
    float* out = (float*)d_out;                   // [8,64,4096]

    float* ws = (float*)d_ws;
    const size_t SECT = (size_t)BATCH * NPTS * 64;      // 2,097,152
    float*  xt    = ws;
    float*  pt    = ws + SECT;
    float*  zt    = ws + 2 * SECT;
    float*  sq    = ws + 3 * SECT;                       // 32768
    float*  S1    = ws + 3 * SECT + 32768;               // 64
    float*  S2    = S1 + 64;
    int*    idx20 = (int*)(ws + 3 * SECT + 32768 + 128); // 655,360 ints
    float*  uA    = ws + 3 * SECT + 32768 + 128 + 655360;
    // union A:
    //   phase 1 (prep..refine): xh | xl | knn32(ushort, B*N*32)
    //   phase 2 (gather..final): tmx | tmn
    ushort* xh    = (ushort*)uA;                         // SECT ushorts
    ushort* xl    = (ushort*)(uA + SECT / 2);            // SECT ushorts
    ushort* knn32 = (ushort*)(uA + SECT);                // B*N*32 ushorts
    float*  tmx   = uA;                                  // SECT floats
    float*  tmn   = uA + SECT;                           // SECT floats
    // total ws use: ~44.7 MB

    hipMemsetAsync(S1, 0, 2 * 64 * sizeof(float), stream);
    k_prep  <<<dim3((BATCH * NPTS) / 256), dim3(256), 0, stream>>>(x, xt, xh, xl, sq);
    k_pz    <<<dim3(BATCH * (NPTS / 64)), dim3(256), 0, stream>>>(xt, W, pt, zt);
    k_knn   <<<dim3(1024), dim3(512), 0, stream>>>(xh, xl, sq, knn32);
    k_refine<<<dim3((BATCH * NPTS) / 8), dim3(256), 0, stream>>>(xt, sq, knn32, idx20);
    k_gather<<<dim3(BATCH * (NPTS / 64)), dim3(256), 0, stream>>>(pt, zt, idx20, tmx, tmn, S1, S2);
    k_final <<<dim3(BATCH * (NPTS / 64)), dim3(256), 0, stream>>>(tmx, tmn, S1, S2, gamma, beta, out);
}